// Round 1
// baseline (17595.129 us; speedup 1.0000x reference)
//
#include <hip/hip_runtime.h>
#include <math.h>

// ---------------- problem constants ----------------
constexpr int kB = 4, kT = 1024, kE = 1024, kH = 16, kHS = 64;
constexpr int kDFF = 4096, kV = 32000, kL = 4;
constexpr int kRows = kB * kT;          // 4096 token rows
constexpr float kEps = 1e-5f;

// ---------------- wave/block reduction helpers ----------------
__device__ __forceinline__ float wave_sum(float v) {
#pragma unroll
  for (int o = 32; o > 0; o >>= 1) v += __shfl_down(v, o, 64);
  return v;
}
__device__ __forceinline__ float wave_max(float v) {
#pragma unroll
  for (int o = 32; o > 0; o >>= 1) v = fmaxf(v, __shfl_down(v, o, 64));
  return v;
}

// ---------------- embedding: x = tok_emb[index] + pos_emb[:T] ----------------
__global__ __launch_bounds__(256) void embed_kernel(
    const int* __restrict__ index, const float* __restrict__ tok,
    const float* __restrict__ pos, float* __restrict__ x) {
  int r = blockIdx.x;                 // 0..4095
  int t = r & (kT - 1);
  int tokid = index[r];
  const float4* tp = (const float4*)(tok + (size_t)tokid * kE);
  const float4* pp = (const float4*)(pos + (size_t)t * kE);
  float4* xp = (float4*)(x + (size_t)r * kE);
  int c = threadIdx.x;                // E/4 == 256 == blockDim
  float4 a = tp[c], b = pp[c];
  xp[c] = make_float4(a.x + b.x, a.y + b.y, a.z + b.z, a.w + b.w);
}

// ---------------- layernorm (one block per row, 256 thr, E=1024) ----------------
__global__ __launch_bounds__(256) void ln_kernel(
    const float* __restrict__ x, const float* __restrict__ g,
    const float* __restrict__ b, float* __restrict__ out) {
  int r = blockIdx.x;
  int tid = threadIdx.x;
  __shared__ float red[4];
  float4 v = ((const float4*)(x + (size_t)r * kE))[tid];
  float s = v.x + v.y + v.z + v.w;
  float ws = wave_sum(s);
  if ((tid & 63) == 0) red[tid >> 6] = ws;
  __syncthreads();
  float mu = (red[0] + red[1] + red[2] + red[3]) * (1.0f / kE);
  __syncthreads();
  float dx0 = v.x - mu, dx1 = v.y - mu, dx2 = v.z - mu, dx3 = v.w - mu;
  float sq = dx0 * dx0 + dx1 * dx1 + dx2 * dx2 + dx3 * dx3;
  float wv = wave_sum(sq);
  if ((tid & 63) == 0) red[tid >> 6] = wv;
  __syncthreads();
  float var = (red[0] + red[1] + red[2] + red[3]) * (1.0f / kE);
  float inv = rsqrtf(var + kEps);
  float4 gg = ((const float4*)g)[tid];
  float4 bb = ((const float4*)b)[tid];
  float4 o;
  o.x = dx0 * inv * gg.x + bb.x;
  o.y = dx1 * inv * gg.y + bb.y;
  o.z = dx2 * inv * gg.z + bb.z;
  o.w = dx3 * inv * gg.w + bb.w;
  ((float4*)(out + (size_t)r * kE))[tid] = o;
}

// ---------------- tiled SGEMM: C = A@B (+bias)(+resid)(relu?) ----------------
// A[M,K], B[K,N], C[M,N] row-major. M%128==0, N%128==0, K%8==0.
constexpr int BM = 128, BN = 128, BK = 8;
__global__ __launch_bounds__(256) void gemm_kernel(
    const float* __restrict__ A, const float* __restrict__ B,
    float* __restrict__ C, const float* __restrict__ bias,
    const float* __restrict__ resid, int M, int N, int K, int relu) {
  __shared__ float As[BK][BM];
  __shared__ float Bs[BK][BN];
  int tid = threadIdx.x;
  int bm = blockIdx.y * BM, bn = blockIdx.x * BN;
  int tx = tid & 15, ty = tid >> 4;         // 16x16 thread grid
  float acc[8][8];
#pragma unroll
  for (int i = 0; i < 8; ++i)
#pragma unroll
    for (int j = 0; j < 8; ++j) acc[i][j] = 0.0f;

  int arow = tid >> 1, acol = (tid & 1) * 4;     // A tile 128x8
  int brow = tid >> 5, bcol = (tid & 31) * 4;    // B tile 8x128

  for (int k0 = 0; k0 < K; k0 += BK) {
    float4 av = *(const float4*)(A + (size_t)(bm + arow) * K + k0 + acol);
    As[acol + 0][arow] = av.x;
    As[acol + 1][arow] = av.y;
    As[acol + 2][arow] = av.z;
    As[acol + 3][arow] = av.w;
    float4 bv = *(const float4*)(B + (size_t)(k0 + brow) * N + bn + bcol);
    *(float4*)&Bs[brow][bcol] = bv;
    __syncthreads();
#pragma unroll
    for (int kk = 0; kk < BK; ++kk) {
      float4 a0 = *(const float4*)&As[kk][ty * 8];
      float4 a1 = *(const float4*)&As[kk][ty * 8 + 4];
      float4 b0 = *(const float4*)&Bs[kk][tx * 8];
      float4 b1 = *(const float4*)&Bs[kk][tx * 8 + 4];
      float ar[8] = {a0.x, a0.y, a0.z, a0.w, a1.x, a1.y, a1.z, a1.w};
      float br[8] = {b0.x, b0.y, b0.z, b0.w, b1.x, b1.y, b1.z, b1.w};
#pragma unroll
      for (int i = 0; i < 8; ++i)
#pragma unroll
        for (int j = 0; j < 8; ++j) acc[i][j] = fmaf(ar[i], br[j], acc[i][j]);
    }
    __syncthreads();
  }

#pragma unroll
  for (int i = 0; i < 8; ++i) {
    int m = bm + ty * 8 + i;
    float* crow = C + (size_t)m * N;
    const float* rrow = resid ? (resid + (size_t)m * N) : nullptr;
#pragma unroll
    for (int j0 = 0; j0 < 8; j0 += 4) {
      int n = bn + tx * 8 + j0;
      float4 r = make_float4(acc[i][j0], acc[i][j0 + 1], acc[i][j0 + 2],
                             acc[i][j0 + 3]);
      if (bias) {
        float4 bv = *(const float4*)(bias + n);
        r.x += bv.x; r.y += bv.y; r.z += bv.z; r.w += bv.w;
      }
      if (rrow) {
        float4 rv = *(const float4*)(rrow + n);
        r.x += rv.x; r.y += rv.y; r.z += rv.z; r.w += rv.w;
      }
      if (relu) {
        r.x = fmaxf(r.x, 0.0f); r.y = fmaxf(r.y, 0.0f);
        r.z = fmaxf(r.z, 0.0f); r.w = fmaxf(r.w, 0.0f);
      }
      *(float4*)(crow + n) = r;
    }
  }
}

// ---------------- causal attention, one block per (b,h,query) ----------------
// q,k,v,o are [B*T, E] with head h occupying cols [h*64, h*64+64)
__global__ __launch_bounds__(256) void attn_kernel(
    const float* __restrict__ q, const float* __restrict__ k,
    const float* __restrict__ v, float* __restrict__ o) {
  int qi = blockIdx.x;          // 0..1023
  int bh = blockIdx.y;          // 0..63
  int b = bh >> 4, h = bh & 15;
  int tid = threadIdx.x;
  __shared__ float qs[kHS];
  __shared__ float sc[kT];
  __shared__ float red[4];
  __shared__ float ored[4][kHS];
  const size_t rowbase = (size_t)b * kT * kE + (size_t)h * kHS;
  if (tid < kHS) qs[tid] = q[rowbase + (size_t)qi * kE + tid];
  __syncthreads();
  int nk = qi + 1;
  const float scale = 0.125f;   // HS^-0.5 = 1/8
  float lmax = -1e30f;
  for (int j = tid; j < nk; j += 256) {
    const float* kr = k + rowbase + (size_t)j * kE;
    float d = 0.0f;
#pragma unroll
    for (int dd = 0; dd < kHS; ++dd) d = fmaf(qs[dd], kr[dd], d);
    d *= scale;
    sc[j] = d;
    lmax = fmaxf(lmax, d);
  }
  float wm = wave_max(lmax);
  if ((tid & 63) == 0) red[tid >> 6] = wm;
  __syncthreads();
  float bmax = fmaxf(fmaxf(red[0], red[1]), fmaxf(red[2], red[3]));
  __syncthreads();
  float lsum = 0.0f;
  for (int j = tid; j < nk; j += 256) {
    float p = expf(sc[j] - bmax);
    sc[j] = p;
    lsum += p;
  }
  float wsum = wave_sum(lsum);
  if ((tid & 63) == 0) red[tid >> 6] = wsum;
  __syncthreads();                       // also fences the sc[] writes
  float inv = 1.0f / (red[0] + red[1] + red[2] + red[3]);
  // pass 2: thread = (jj, d) with jj = tid>>6 in 0..3, d = tid&63
  int d = tid & 63, jj = tid >> 6;
  float acc = 0.0f;
  for (int j = jj; j < nk; j += 4)
    acc = fmaf(sc[j], v[rowbase + (size_t)j * kE + d], acc);
  ored[jj][d] = acc;
  __syncthreads();
  if (tid < kHS) {
    float r = ored[0][tid] + ored[1][tid] + ored[2][tid] + ored[3][tid];
    o[rowbase + (size_t)qi * kE + tid] = r * inv;
  }
}

// ---------------- loss stage 1: per-row -logp[target] ----------------
__global__ __launch_bounds__(256) void loss_row_kernel(
    const float* __restrict__ logits, const int* __restrict__ targets,
    float* __restrict__ rowloss) {
  int r = blockIdx.x;
  int tid = threadIdx.x;
  const float4* lr = (const float4*)(logits + (size_t)r * kV);
  __shared__ float red[4];
  float lmax = -1e30f;
  for (int c = tid; c < kV / 4; c += 256) {
    float4 v = lr[c];
    lmax = fmaxf(lmax, fmaxf(fmaxf(v.x, v.y), fmaxf(v.z, v.w)));
  }
  float wm = wave_max(lmax);
  if ((tid & 63) == 0) red[tid >> 6] = wm;
  __syncthreads();
  float bmax = fmaxf(fmaxf(red[0], red[1]), fmaxf(red[2], red[3]));
  __syncthreads();
  float lsum = 0.0f;
  for (int c = tid; c < kV / 4; c += 256) {
    float4 v = lr[c];
    lsum += expf(v.x - bmax) + expf(v.y - bmax) + expf(v.z - bmax) +
            expf(v.w - bmax);
  }
  float ws = wave_sum(lsum);
  if ((tid & 63) == 0) red[tid >> 6] = ws;
  __syncthreads();
  if (tid == 0) {
    float bsum = red[0] + red[1] + red[2] + red[3];
    float tgt = logits[(size_t)r * kV + targets[r]];
    rowloss[r] = -(tgt - bmax - logf(bsum));
  }
}

// ---------------- loss stage 2: mean over 4096 rows ----------------
__global__ __launch_bounds__(256) void loss_final_kernel(
    const float* __restrict__ rowloss, float* __restrict__ out) {
  int tid = threadIdx.x;
  __shared__ float red[4];
  float s = 0.0f;
  for (int r = tid; r < kRows; r += 256) s += rowloss[r];
  float ws = wave_sum(s);
  if ((tid & 63) == 0) red[tid >> 6] = ws;
  __syncthreads();
  if (tid == 0)
    out[0] = (red[0] + red[1] + red[2] + red[3]) * (1.0f / kRows);
}

// ---------------- host-side orchestration ----------------
extern "C" void kernel_launch(void* const* d_in, const int* in_sizes, int n_in,
                              void* d_out, int out_size, void* d_ws,
                              size_t ws_size, hipStream_t stream) {
  const int* index = (const int*)d_in[0];
  const int* targets = (const int*)d_in[1];
  const float* tok_emb = (const float*)d_in[2];
  const float* pos_emb = (const float*)d_in[3];
  const float* Wq = (const float*)d_in[4];
  const float* Wk = (const float*)d_in[5];
  const float* Wv = (const float*)d_in[6];
  const float* Wo = (const float*)d_in[7];
  const float* bo = (const float*)d_in[8];
  const float* ln0_g = (const float*)d_in[9];
  const float* ln0_b = (const float*)d_in[10];
  const float* ln1_g = (const float*)d_in[11];
  const float* ln1_b = (const float*)d_in[12];
  const float* W1 = (const float*)d_in[13];
  const float* b1 = (const float*)d_in[14];
  const float* W2 = (const float*)d_in[15];
  const float* b2 = (const float*)d_in[16];
  const float* fln_g = (const float*)d_in[17];
  const float* fln_b = (const float*)d_in[18];
  const float* lmh_W = (const float*)d_in[19];
  const float* lmh_b = (const float*)d_in[20];

  float* logits = (float*)d_out;                       // [4096, 32000]
  float* loss = logits + (size_t)kRows * kV;           // scalar

  // workspace layout (floats): x | h | q k v o (=ff aliased) | rowloss
  float* x = (float*)d_ws;
  float* h = x + (size_t)kRows * kE;
  float* qb = h + (size_t)kRows * kE;
  float* kb = qb + (size_t)kRows * kE;
  float* vb = kb + (size_t)kRows * kE;
  float* ob = vb + (size_t)kRows * kE;
  float* ff = qb;                    // 4096*4096 floats == q+k+v+o region
  float* rowloss = ob + (size_t)kRows * kE;

  dim3 blk(256);
  dim3 gE(kE / BN, kRows / BM);      // N=1024 GEMMs
  dim3 gF(kDFF / BN, kRows / BM);    // N=4096 GEMM
  dim3 gV(kV / BN, kRows / BM);      // N=32000 GEMM (250 x 32)

  embed_kernel<<<kRows, blk, 0, stream>>>(index, tok_emb, pos_emb, x);

  for (int l = 0; l < kL; ++l) {
    ln_kernel<<<kRows, blk, 0, stream>>>(x, ln0_g + l * kE, ln0_b + l * kE, h);
    gemm_kernel<<<gE, blk, 0, stream>>>(h, Wq + (size_t)l * kE * kE, qb,
                                        nullptr, nullptr, kRows, kE, kE, 0);
    gemm_kernel<<<gE, blk, 0, stream>>>(h, Wk + (size_t)l * kE * kE, kb,
                                        nullptr, nullptr, kRows, kE, kE, 0);
    gemm_kernel<<<gE, blk, 0, stream>>>(h, Wv + (size_t)l * kE * kE, vb,
                                        nullptr, nullptr, kRows, kE, kE, 0);
    attn_kernel<<<dim3(kT, kB * kH), blk, 0, stream>>>(qb, kb, vb, ob);
    gemm_kernel<<<gE, blk, 0, stream>>>(ob, Wo + (size_t)l * kE * kE, x,
                                        bo + l * kE, x, kRows, kE, kE, 0);
    ln_kernel<<<kRows, blk, 0, stream>>>(x, ln1_g + l * kE, ln1_b + l * kE, h);
    gemm_kernel<<<gF, blk, 0, stream>>>(h, W1 + (size_t)l * kE * kDFF, ff,
                                        b1 + l * kDFF, nullptr, kRows, kDFF,
                                        kE, 1);
    gemm_kernel<<<gE, blk, 0, stream>>>(ff, W2 + (size_t)l * kDFF * kE, x,
                                        b2 + l * kE, x, kRows, kE, kDFF, 0);
  }

  ln_kernel<<<kRows, blk, 0, stream>>>(x, fln_g, fln_b, h);
  gemm_kernel<<<gV, blk, 0, stream>>>(h, lmh_W, logits, lmh_b, nullptr, kRows,
                                      kV, kE, 0);
  loss_row_kernel<<<kRows, blk, 0, stream>>>(logits, targets, rowloss);
  loss_final_kernel<<<1, blk, 0, stream>>>(rowloss, loss);
}